// Round 3
// baseline (839.572 us; speedup 1.0000x reference)
//
#include <hip/hip_runtime.h>
#include <math.h>

#define NQ 12
#define MULT 3.14159253438047729f

// qubit q <-> state bit (11-q). CNOT ring, range r, sequential with updated controls.
__host__ __device__ constexpr int cnotf(int s, int r) {
    for (int q = 0; q < NQ; ++q) {
        int t = q + r; if (t >= NQ) t -= NQ;
        s ^= ((s >> (11 - q)) & 1) << (11 - t);
    }
    return s;
}

// GF(2)-linear LDS placement: amp s -> byte offset of float2 in 32KB buffer.
// pos = s ^ ((s>>6)&63). Gives optimal (4 words/bank) b64 patterns for all
// three static transpose access patterns.
__host__ __device__ constexpr int posb(int s) {
    return (s ^ ((s >> 6) & 63)) << 3;
}

// Precompute 144 Rot matrices (u00,u01,u10,u11 as re,im pairs) + 6 rings x 12
// posb-mapped GF(2) columns for the folded CNOT write.
__global__ void vqc_prep(const float* __restrict__ th, float* __restrict__ gates,
                         int* __restrict__ ptab) {
    int idx = blockIdx.x * blockDim.x + threadIdx.x;
    if (idx < 144) {
        const float* w = th + idx * 3;
        float phi = w[0], tht = w[1], om = w[2];
        float st, ct, spo, cpo, smo, cmo;
        sincosf(0.5f * tht, &st, &ct);
        sincosf(0.5f * (phi + om), &spo, &cpo);
        sincosf(0.5f * (phi - om), &smo, &cmo);
        float* o = gates + idx * 8;
        o[0] = ct * cpo;  o[1] = -ct * spo;   // u00
        o[2] = -st * cmo; o[3] = -st * smo;   // u01
        o[4] = st * cmo;  o[5] = -st * smo;   // u10
        o[6] = ct * cpo;  o[7] = ct * spo;    // u11
    } else if (idx < 144 + 72) {
        int e = idx - 144;
        int d = e / 12, m = e % 12;
        ptab[e] = posb(cnotf(1 << m, d + 1));
    }
}

// One 1q gate on register-bit B across 16 float2 amps.
// ga = (u00r,u00i,u01r,u01i), gb = (u10r,u10i,u11r,u11i)
template <int B>
__device__ __forceinline__ void apply1(float2* a, float4 ga, float4 gb) {
#pragma unroll
    for (int j = 0; j < 16; ++j) {
        if (j & B) continue;
        float2 x0 = a[j], x1 = a[j | B];
        float2 n0, n1;
        n0.x = ga.x * x0.x - ga.y * x0.y + ga.z * x1.x - ga.w * x1.y;
        n0.y = ga.x * x0.y + ga.y * x0.x + ga.z * x1.y + ga.w * x1.x;
        n1.x = gb.x * x0.x - gb.y * x0.y + gb.z * x1.x - gb.w * x1.y;
        n1.y = gb.x * x0.y + gb.y * x0.x + gb.z * x1.y + gb.w * x1.x;
        a[j] = n0;
        a[j | B] = n1;
    }
}

__global__ __launch_bounds__(256, 4) void vqc_main(
        const float* __restrict__ x,
        const float* __restrict__ gates,
        const int* __restrict__ ptab,
        float* __restrict__ out, int nstates) {
    __shared__ float2 st[4096];   // 32 KB state
    __shared__ float4 gl[288];    // 4.5 KB gates (144 gates x 2 float4)
    __shared__ float ang[64];     // cross-wave expval partials + angles

    const int t = threadIdx.x;
    const int lane = t & 63;
    const int wv = t >> 6;
    const int b = blockIdx.x;

    // stage all gates into LDS once
    {
        const float4* g4 = (const float4*)gates;
        gl[t] = g4[t];
        if (t < 32) gl[256 + t] = g4[256 + t];
    }

    char* sbp = (char*)st;
    const int base0 = posb(t);                             // A-own: s = (j<<8)|t
    const int baseB = posb((t & 15) | ((t >> 4) << 8));    // B-own: s = lo | j<<4 | hi<<8
    const int baseC = posb(((t & 15) << 4) | ((t >> 4) << 8));  // C-own: s = j | lo<<4 | hi<<8

    float2 a[16];

#pragma unroll 1
    for (int l = 0; l < 2; ++l) {
        float myang = 0.0f;
        if (l == 0) {
            if (lane < NQ) myang = x[b * NQ + lane];
        } else {
            if (lane < NQ) myang = ang[48 + lane];
        }
        float sv, cv;
        sincosf(0.5f * myang, &sv, &cv);
        float cq[NQ], sq[NQ];
#pragma unroll
        for (int q = 0; q < NQ; ++q) {
            cq[q] = __shfl(cv, q, 64);
            sq[q] = __shfl(sv, q, 64);
        }
        __syncthreads();  // gate preload (l==0) / ang reads (l==1) complete

        // ---- product-state init (A-own): t bit k -> qubit 11-k, j bit k -> qubit 3-k
        float pl = 1.0f;
#pragma unroll
        for (int k = 0; k < 8; ++k) pl *= ((t >> k) & 1) ? sq[11 - k] : cq[11 - k];
#pragma unroll
        for (int j = 0; j < 16; ++j) {
            float f = pl;
#pragma unroll
            for (int k = 0; k < 4; ++k) f *= ((j >> k) & 1) ? sq[3 - k] : cq[3 - k];
            a[j] = make_float2(f, 0.0f);
        }

#pragma unroll 1
        for (int d = 0; d < 6; ++d) {
            // ring columns for this depth (uniform -> scalar loads)
            int pc[12];
#pragma unroll
            for (int k = 0; k < 12; ++k) pc[k] = ptab[d * 12 + k];
            int baseP = 0;
#pragma unroll
            for (int k = 0; k < 4; ++k) if ((t >> k) & 1) baseP ^= pc[4 + k];
#pragma unroll
            for (int k = 0; k < 4; ++k) if ((t >> (4 + k)) & 1) baseP ^= pc[8 + k];

            const float4* gd = gl + (l * 6 + d) * 24;

            // ---- phase A: qubits 0..3 (local j bits 8,4,2,1) ----
            {
                float4 G[8];
#pragma unroll
                for (int k = 0; k < 8; ++k) G[k] = gd[k];
                apply1<8>(a, G[0], G[1]);
                apply1<4>(a, G[2], G[3]);
                apply1<2>(a, G[4], G[5]);
                apply1<1>(a, G[6], G[7]);
            }
            // T1: write A-own, read B-own
#pragma unroll
            for (int j = 0; j < 16; ++j)
                *(float2*)(sbp + (base0 ^ posb(j << 8))) = a[j];
            __syncthreads();
#pragma unroll
            for (int j = 0; j < 16; ++j)
                a[j] = *(const float2*)(sbp + (baseB ^ posb(j << 4)));
            __syncthreads();

            // ---- phase B: qubits 4..7 ----
            {
                float4 G[8];
#pragma unroll
                for (int k = 0; k < 8; ++k) G[k] = gd[8 + k];
                apply1<8>(a, G[0], G[1]);
                apply1<4>(a, G[2], G[3]);
                apply1<2>(a, G[4], G[5]);
                apply1<1>(a, G[6], G[7]);
            }
            // T2: write B-own, read C-own
#pragma unroll
            for (int j = 0; j < 16; ++j)
                *(float2*)(sbp + (baseB ^ posb(j << 4))) = a[j];
            __syncthreads();
#pragma unroll
            for (int j = 0; j < 16; ++j)
                a[j] = *(const float2*)(sbp + (baseC ^ posb(j)));
            __syncthreads();

            // ---- phase C: qubits 8..11 ----
            {
                float4 G[8];
#pragma unroll
                for (int k = 0; k < 8; ++k) G[k] = gd[16 + k];
                apply1<8>(a, G[0], G[1]);
                apply1<4>(a, G[2], G[3]);
                apply1<2>(a, G[4], G[5]);
                apply1<1>(a, G[6], G[7]);
            }
            // T3: write C-own with CNOT ring folded (new[f(s)] = old[s]), read A-own
#pragma unroll
            for (int j = 0; j < 16; ++j) {
                int addr = baseP;
                if (j & 1) addr ^= pc[0];
                if (j & 2) addr ^= pc[1];
                if (j & 4) addr ^= pc[2];
                if (j & 8) addr ^= pc[3];
                *(float2*)(sbp + addr) = a[j];
            }
            __syncthreads();
#pragma unroll
            for (int j = 0; j < 16; ++j)
                a[j] = *(const float2*)(sbp + (base0 ^ posb(j << 8)));
            __syncthreads();
        }

        // ---- readout: <Z_q> ----
        float T = 0.f, e0 = 0.f, e1 = 0.f, e2 = 0.f, e3 = 0.f;
#pragma unroll
        for (int j = 0; j < 16; ++j) {
            float p = a[j].x * a[j].x + a[j].y * a[j].y;
            T += p;
            e3 += (j & 1) ? -p : p;   // j bit 0 <-> s8 <-> qubit 3
            e2 += (j & 2) ? -p : p;
            e1 += (j & 4) ? -p : p;
            e0 += (j & 8) ? -p : p;
        }
        float e[NQ];
        e[0] = e0; e[1] = e1; e[2] = e2; e[3] = e3;
#pragma unroll
        for (int q = 4; q < NQ; ++q)
            e[q] = ((t >> (11 - q)) & 1) ? -T : T;
#pragma unroll
        for (int q = 0; q < NQ; ++q) {
            float v = e[q];
            v += __shfl_down(v, 32, 64);
            v += __shfl_down(v, 16, 64);
            v += __shfl_down(v, 8, 64);
            v += __shfl_down(v, 4, 64);
            v += __shfl_down(v, 2, 64);
            v += __shfl_down(v, 1, 64);
            e[q] = v;
        }
        if (lane == 0) {
#pragma unroll
            for (int q = 0; q < NQ; ++q) ang[wv * NQ + q] = e[q];
        }
        __syncthreads();
        if (l == 0) {
            if (t < NQ) {
                float s = ang[t] + ang[NQ + t] + ang[2 * NQ + t] + ang[3 * NQ + t];
                ang[48 + t] = s;
            }
            __syncthreads();
        } else {
            if (t >= 3 && t < 9) {
                float s = ang[t] + ang[NQ + t] + ang[2 * NQ + t] + ang[3 * NQ + t];
                out[b * 6 + (t - 3)] = s * MULT;
            }
        }
    }
}

extern "C" void kernel_launch(void* const* d_in, const int* in_sizes, int n_in,
                              void* d_out, int out_size, void* d_ws, size_t ws_size,
                              hipStream_t stream) {
    const float* x = (const float*)d_in[0];
    const float* th = (const float*)d_in[1];
    float* outp = (float*)d_out;
    float* gates = (float*)d_ws;                // 144*8 floats = 4608 B
    int* ptab = (int*)((char*)d_ws + 4608);     // 72 ints = 288 B

    int batch = in_sizes[0] / NQ;

    hipLaunchKernelGGL(vqc_prep, dim3(1), dim3(256), 0, stream, th, gates, ptab);
    hipLaunchKernelGGL(vqc_main, dim3(batch), dim3(256), 0, stream, x, gates, ptab,
                       outp, batch);
}

// Round 5
// 171.621 us; speedup vs baseline: 4.8920x; 4.8920x over previous
//
#include <hip/hip_runtime.h>
#include <math.h>

#define NQ 12
#define MULT 3.1415925343968237f

typedef _Float16 f16x8 __attribute__((ext_vector_type(8)));
typedef _Float16 f16x2 __attribute__((ext_vector_type(2)));
typedef float f32x4 __attribute__((ext_vector_type(4)));

// pack two f32 -> pk-rtz f16x2 as raw u32 (avoids __fp16/_Float16 vector mismatch)
static __device__ __forceinline__ unsigned int pkh(float a, float b) {
    auto h = __builtin_amdgcn_cvt_pkrtz(a, b);
    return __builtin_bit_cast(unsigned int, h);
}

// qubit q <-> state bit (11-q). CNOT ring, range r, sequential (updated controls).
__host__ __device__ constexpr int cnotf(int s, int r) {
    for (int q = 0; q < NQ; ++q) {
        int tq = q + r; if (tq >= NQ) tq -= NQ;
        s ^= ((s >> (11 - q)) & 1) << (11 - tq);
    }
    return s;
}

// GF(2)-bijective LDS word map. Roles per layout L_p: I = group(p) nibble
// (reader-inner), u = group(p-1) (writer-inner), n = group(p+1).
// Bank bits w[4:2] mix I-high, u, n so b128 reads hit 8 words/bank (optimal)
// and b32 writes are 2-way (free). w[1:0]=I[1:0] keeps b128 reads contiguous.
__host__ __device__ constexpr int wordL(int I, int u, int n) {
    int I2 = (I >> 2) & 1, I3 = (I >> 3) & 1;
    int u0 = u & 1, u1 = (u >> 1) & 1, u2 = (u >> 2) & 1, u3 = (u >> 3) & 1;
    int n0 = n & 1, n1 = (n >> 1) & 1, n2 = (n >> 2) & 1, n3 = (n >> 3) & 1;
    return (I & 3) | ((I2 ^ u1 ^ n0) << 2) | ((I3 ^ u2 ^ n1) << 3) |
           ((I2 ^ u2 ^ n2) << 4) | (u0 << 5) | (u3 << 6) | (n0 << 7) |
           (n1 << 8) | (n2 << 9) | (n3 << 10) | (u1 << 11);
}

// Prep: build 36 fused 16x16 complex unitaries as per-lane MFMA A-fragments
// (f16, 2 row-tiles each), plus CNOT-perm basis deltas in L_A word space.
__global__ void vqc_prep(const float* __restrict__ th, _Float16* __restrict__ frag,
                         int* __restrict__ ptabd) {
    int gid = blockIdx.x * 256 + threadIdx.x;
    int job = gid >> 6, lane = gid & 63;
    if (job < 72) {
        int pg = job >> 1, R = job & 1;
        int layer = pg / 18, rem = pg % 18, depth = rem / 3, ph = rem % 3;
        float g[4][2][2][2];
        for (int j = 0; j < 4; ++j) {
            int q = 4 * ph + j;
            const float* w = th + (((layer * 6 + depth) * 12 + q) * 3);
            float phi = w[0], tht = w[1], om = w[2];
            float st, ct, spo, cpo, smo, cmo;
            sincosf(0.5f * tht, &st, &ct);
            sincosf(0.5f * (phi + om), &spo, &cpo);
            sincosf(0.5f * (phi - om), &smo, &cmo);
            g[j][0][0][0] = ct * cpo;  g[j][0][0][1] = -ct * spo;
            g[j][0][1][0] = -st * cmo; g[j][0][1][1] = -st * smo;
            g[j][1][0][0] = st * cmo;  g[j][1][0][1] = -st * smo;
            g[j][1][1][0] = ct * cpo;  g[j][1][1][1] = ct * spo;
        }
        int m = 16 * R + (lane & 15);
        int u = m >> 1, v = m & 1;
        float Wr[4], Wi[4];
        for (int c = 0; c < 4; ++c) {
            int up = (lane >> 4) * 4 + c;
            float ar = 1.f, ai = 0.f;
            for (int j = 0; j < 4; ++j) {
                int ub = (u >> (3 - j)) & 1, vb = (up >> (3 - j)) & 1;
                float gr = g[j][ub][vb][0], gi = g[j][ub][vb][1];
                float nr = ar * gr - ai * gi, ni = ar * gi + ai * gr;
                ar = nr; ai = ni;
            }
            Wr[c] = ar; Wi[c] = ai;
        }
        _Float16* o = frag + ((size_t)job * 64 + lane) * 8;
        for (int i = 0; i < 8; ++i) {
            int c = i >> 1, vp = i & 1;
            float val = (v == vp) ? Wr[c] : (v == 0 ? -Wi[c] : Wi[c]);
            o[i] = (_Float16)val;
        }
    }
    if (blockIdx.x == 0 && threadIdx.x < 72) {
        int d = threadIdx.x / 12, bb = threadIdx.x % 12;
        int sp = cnotf(1 << bb, d + 1);
        ptabd[threadIdx.x] = wordL((sp >> 8) & 15, sp & 15, (sp >> 4) & 15);
    }
}

__global__ __launch_bounds__(256, 4) void vqc_main(
        const float* __restrict__ x, const uint4* __restrict__ frag,
        const int* __restrict__ ptabd, float* __restrict__ out, int nst) {
    __shared__ __align__(16) unsigned int sbuf[8192];  // 2 x 16KB f16 state
    __shared__ float ang[64];
    const int t = threadIdx.x, lane = t & 63, wv = t >> 6, b = blockIdx.x;
    if (b >= nst) return;

    // per-lane invariant word bases (wordL is GF(2)-linear => XOR-decomposable)
    const int rbase = wordL(4 * (lane >> 4), 4 * wv, lane & 15);  // reads/init/readout
    const int wbase = wordL(lane & 15, 2 * (lane >> 4), 4 * wv);  // A/B-phase writes
    constexpr int RC[4] = {wordL(0,0,0), wordL(0,1,0), wordL(0,2,0), wordL(0,3,0)};
    constexpr int WCt[4] = {wordL(0,0,0), wordL(0,0,1), wordL(0,0,2), wordL(0,0,3)};

    int cur = 0;
    float myang = 0.f;
#pragma unroll 1
    for (int l = 0; l < 2; ++l) {
        if (l == 0) { if (lane < NQ) myang = x[b * NQ + lane]; }
        else        { if (lane < NQ) myang = ang[48 + lane]; }
        float sv, cv;
        sincosf(0.5f * myang, &sv, &cv);
        float cq[NQ], sq[NQ];
#pragma unroll
        for (int q = 0; q < NQ; ++q) { cq[q] = __shfl(cv, q, 64); sq[q] = __shfl(sv, q, 64); }
        __syncthreads();

        // ---- init product state (f16, layout L_A, buffer cur) ----
        {
            float Pn = 1.f;
#pragma unroll
            for (int j = 0; j < 4; ++j) Pn *= ((lane >> j) & 1) ? sq[7 - j] : cq[7 - j];
            float Phi = (((lane >> 4) & 1) ? sq[1] : cq[1]) * (((lane >> 4) & 2) ? sq[0] : cq[0]);
            float pre = Pn * Phi;
            float Plo0 = cq[3] * cq[2], Plo1 = sq[3] * cq[2];
            float Plo2 = cq[3] * sq[2], Plo3 = sq[3] * sq[2];
#pragma unroll
            for (int t2 = 0; t2 < 4; ++t2) {
                float Pu = ((t2 & 1) ? sq[11] : cq[11]) * ((t2 & 2) ? sq[10] : cq[10]) *
                           ((wv & 1) ? sq[9] : cq[9]) * ((wv & 2) ? sq[8] : cq[8]);
                float base = pre * Pu;
                uint4 w;
                w.x = pkh(base * Plo0, 0.f);
                w.y = pkh(base * Plo1, 0.f);
                w.z = pkh(base * Plo2, 0.f);
                w.w = pkh(base * Plo3, 0.f);
                *(uint4*)&sbuf[cur * 4096 + (rbase ^ RC[t2])] = w;
            }
        }
        __syncthreads();

#pragma unroll 1
        for (int d = 0; d < 6; ++d) {
            const int* pdp = ptabd + d * 12;
            int p0 = pdp[0], p1 = pdp[1], p2 = pdp[2], p3 = pdp[3];
            int p4 = pdp[4], p5 = pdp[5], p6 = pdp[6], p7 = pdp[7];
            int p8 = pdp[8], p9 = pdp[9], p10 = pdp[10], p11 = pdp[11];
            int pb = 0;  // lane part of CNOT-permuted write base (phase C)
            if (lane & 1)  pb ^= p8;
            if (lane & 2)  pb ^= p9;
            if (lane & 4)  pb ^= p10;
            if (lane & 8)  pb ^= p11;
            if (lane & 16) pb ^= p1;
            if (lane & 32) pb ^= p2;
            if (wv & 1)    pb ^= p6;
            if (wv & 2)    pb ^= p7;
#pragma unroll
            for (int ph = 0; ph < 3; ++ph) {
                const int pg = (l * 6 + d) * 3 + ph;
                f16x8 a0 = __builtin_bit_cast(f16x8, frag[(pg * 2 + 0) * 64 + lane]);
                f16x8 a1 = __builtin_bit_cast(f16x8, frag[(pg * 2 + 1) * 64 + lane]);
                const unsigned int* rp = sbuf + cur * 4096;
                f32x4 zero = {0.f, 0.f, 0.f, 0.f};
                f32x4 ac[2][4];
#pragma unroll
                for (int t2 = 0; t2 < 4; ++t2) {
                    f16x8 bf = __builtin_bit_cast(f16x8, *(const uint4*)&rp[rbase ^ RC[t2]]);
                    ac[0][t2] = __builtin_amdgcn_mfma_f32_16x16x32_f16(a0, bf, zero, 0, 0, 0);
                    ac[1][t2] = __builtin_amdgcn_mfma_f32_16x16x32_f16(a1, bf, zero, 0, 0, 0);
                }
                unsigned int* wp = sbuf + (cur ^ 1) * 4096;
                if (ph < 2) {
#pragma unroll
                    for (int R = 0; R < 2; ++R)
#pragma unroll
                        for (int t2 = 0; t2 < 4; ++t2)
#pragma unroll
                            for (int pr = 0; pr < 2; ++pr) {
                                int word = wbase ^ (32 * pr + 64 * R) ^ WCt[t2];
                                wp[word] = pkh(ac[R][t2][2 * pr], ac[R][t2][2 * pr + 1]);
                            }
                } else {  // phase C: CNOT ring folded into write permutation
#pragma unroll
                    for (int R = 0; R < 2; ++R)
#pragma unroll
                        for (int t2 = 0; t2 < 4; ++t2)
#pragma unroll
                            for (int pr = 0; pr < 2; ++pr) {
                                int sc = (R ? p3 : 0) ^ (pr ? p0 : 0) ^
                                         ((t2 & 1) ? p4 : 0) ^ ((t2 & 2) ? p5 : 0);
                                int word = pb ^ sc;
                                wp[word] = pkh(ac[R][t2][2 * pr], ac[R][t2][2 * pr + 1]);
                            }
                }
                __syncthreads();
                cur ^= 1;
            }
        }

        // ---- readout from buffer cur (layout L_A) ----
        {
            const unsigned int* rp = sbuf + cur * 4096;
            float P = 0.f, e2 = 0.f, e3 = 0.f, Tt[4];
#pragma unroll
            for (int t2 = 0; t2 < 4; ++t2) {
                uint4 v = *(const uint4*)&rp[rbase ^ RC[t2]];
                unsigned int arr[4] = {v.x, v.y, v.z, v.w};
                float tl = 0.f;
#pragma unroll
                for (int i = 0; i < 4; ++i) {
                    f16x2 h = __builtin_bit_cast(f16x2, arr[i]);
                    float re = (float)h[0], im = (float)h[1];
                    float p = re * re + im * im;
                    tl += p;
                    e2 += (i & 2) ? -p : p;
                    e3 += (i & 1) ? -p : p;
                }
                Tt[t2] = tl; P += tl;
            }
            float r[12];
            r[0] = (lane & 32) ? -P : P;  // q0 <- I bit3
            r[1] = (lane & 16) ? -P : P;  // q1 <- I bit2
            r[2] = e2; r[3] = e3;
            r[4] = (lane & 8) ? -P : P;   // q4 <- n bit3
            r[5] = (lane & 4) ? -P : P;
            r[6] = (lane & 2) ? -P : P;
            r[7] = (lane & 1) ? -P : P;
            r[8] = Tt[0]; r[9] = Tt[1]; r[10] = Tt[2]; r[11] = Tt[3];
#pragma unroll
            for (int k = 0; k < 12; ++k) {
#pragma unroll
                for (int m = 1; m < 64; m <<= 1) r[k] += __shfl_xor(r[k], m, 64);
            }
            if (lane == 0) {
#pragma unroll
                for (int k = 0; k < 12; ++k) ang[wv * 12 + k] = r[k];
            }
            __syncthreads();
            if (t < NQ) {
                float E = 0.f;
                if (t < 8) {
                    E = ang[t] + ang[12 + t] + ang[24 + t] + ang[36 + t];
                } else {
#pragma unroll
                    for (int wvi = 0; wvi < 4; ++wvi)
#pragma unroll
                        for (int t2 = 0; t2 < 4; ++t2) {
                            float v = ang[wvi * 12 + 8 + t2];
                            int Tg = 4 * wvi + t2;
                            int bit = (t == 8) ? ((Tg >> 3) & 1) : (t == 9) ? ((Tg >> 2) & 1)
                                    : (t == 10) ? ((Tg >> 1) & 1) : (Tg & 1);
                            E += bit ? -v : v;
                        }
                }
                if (l == 0) ang[48 + t] = E;
                else if (t >= 3 && t < 9) out[b * 6 + (t - 3)] = E * MULT;
            }
            __syncthreads();
        }
    }
}

extern "C" void kernel_launch(void* const* d_in, const int* in_sizes, int n_in,
                              void* d_out, int out_size, void* d_ws, size_t ws_size,
                              hipStream_t stream) {
    const float* x = (const float*)d_in[0];
    const float* th = (const float*)d_in[1];
    float* outp = (float*)d_out;
    _Float16* fragh = (_Float16*)d_ws;                    // 36*2*64*8 f16 = 73728 B
    int* ptabd = (int*)((char*)d_ws + 73728);             // 72 ints = 288 B

    int batch = in_sizes[0] / NQ;

    hipLaunchKernelGGL(vqc_prep, dim3(18), dim3(256), 0, stream, th, fragh, ptabd);
    hipLaunchKernelGGL(vqc_main, dim3(batch), dim3(256), 0, stream, x,
                       (const uint4*)fragh, ptabd, outp, batch);
}

// Round 11
// 170.203 us; speedup vs baseline: 4.9328x; 1.0083x over previous
//
#include <hip/hip_runtime.h>
#include <math.h>

#define NQ 12
#define MULT 3.1415925343968237f

typedef _Float16 f16x8 __attribute__((ext_vector_type(8)));
typedef _Float16 f16x2 __attribute__((ext_vector_type(2)));
typedef float f32x4 __attribute__((ext_vector_type(4)));

// pack two f32 -> pk-rtz f16x2 as raw u32
static __device__ __forceinline__ unsigned int pkh(float a, float b) {
    auto h = __builtin_amdgcn_cvt_pkrtz(a, b);
    return __builtin_bit_cast(unsigned int, h);
}

// qubit q <-> state bit (11-q). CNOT ring, range r, sequential (updated controls).
__host__ __device__ constexpr int cnotf(int s, int r) {
    for (int q = 0; q < NQ; ++q) {
        int tq = q + r; if (tq >= NQ) tq -= NQ;
        s ^= ((s >> (11 - q)) & 1) << (11 - tq);
    }
    return s;
}

// GF(2)-bijective LDS word map (round-5 derivation).
__host__ __device__ constexpr int wordL(int I, int u, int n) {
    int I2 = (I >> 2) & 1, I3 = (I >> 3) & 1;
    int u0 = u & 1, u1 = (u >> 1) & 1, u2 = (u >> 2) & 1, u3 = (u >> 3) & 1;
    int n0 = n & 1, n1 = (n >> 1) & 1, n2 = (n >> 2) & 1, n3 = (n >> 3) & 1;
    return (I & 3) | ((I2 ^ u1 ^ n0) << 2) | ((I3 ^ u2 ^ n1) << 3) |
           ((I2 ^ u2 ^ n2) << 4) | (u0 << 5) | (u3 << 6) | (n0 << 7) |
           (n1 << 8) | (n2 << 9) | (n3 << 10) | (u1 << 11);
}

// Prep: build 36 fused 16x16 complex unitaries as per-lane MFMA A-fragments
// (f16, 2 row-tiles each), plus CNOT-perm basis deltas in L_A word space.
__global__ void vqc_prep(const float* __restrict__ th, _Float16* __restrict__ frag,
                         int* __restrict__ ptabd) {
    int gid = blockIdx.x * 256 + threadIdx.x;
    int job = gid >> 6, lane = gid & 63;
    if (job < 72) {
        int pg = job >> 1, R = job & 1;
        int layer = pg / 18, rem = pg % 18, depth = rem / 3, ph = rem % 3;
        float g[4][2][2][2];
        for (int j = 0; j < 4; ++j) {
            int q = 4 * ph + j;
            const float* w = th + (((layer * 6 + depth) * 12 + q) * 3);
            float phi = w[0], tht = w[1], om = w[2];
            float st, ct, spo, cpo, smo, cmo;
            sincosf(0.5f * tht, &st, &ct);
            sincosf(0.5f * (phi + om), &spo, &cpo);
            sincosf(0.5f * (phi - om), &smo, &cmo);
            g[j][0][0][0] = ct * cpo;  g[j][0][0][1] = -ct * spo;
            g[j][0][1][0] = -st * cmo; g[j][0][1][1] = -st * smo;
            g[j][1][0][0] = st * cmo;  g[j][1][0][1] = -st * smo;
            g[j][1][1][0] = ct * cpo;  g[j][1][1][1] = ct * spo;
        }
        int m = 16 * R + (lane & 15);
        int u = m >> 1, v = m & 1;
        float Wr[4], Wi[4];
        for (int c = 0; c < 4; ++c) {
            int up = (lane >> 4) * 4 + c;
            float ar = 1.f, ai = 0.f;
            for (int j = 0; j < 4; ++j) {
                int ub = (u >> (3 - j)) & 1, vb = (up >> (3 - j)) & 1;
                float gr = g[j][ub][vb][0], gi = g[j][ub][vb][1];
                float nr = ar * gr - ai * gi, ni = ar * gi + ai * gr;
                ar = nr; ai = ni;
            }
            Wr[c] = ar; Wi[c] = ai;
        }
        _Float16* o = frag + ((size_t)job * 64 + lane) * 8;
        for (int i = 0; i < 8; ++i) {
            int c = i >> 1, vp = i & 1;
            float val = (v == vp) ? Wr[c] : (v == 0 ? -Wi[c] : Wi[c]);
            o[i] = (_Float16)val;
        }
    }
    if (blockIdx.x == 0 && threadIdx.x < 72) {
        int d = threadIdx.x / 12, bb = threadIdx.x % 12;
        int sp = cnotf(1 << bb, d + 1);
        ptabd[threadIdx.x] = wordL((sp >> 8) & 15, sp & 15, (sp >> 4) & 15);
    }
}

__global__ __launch_bounds__(256, 4) void vqc_main(
        const float* __restrict__ x, const uint4* __restrict__ frag,
        const int* __restrict__ ptabd, float* __restrict__ out, int nst) {
    __shared__ __align__(16) unsigned int sbuf[8192];  // 2 x 16KB f16 state
    __shared__ float ang[64];
    const int t = threadIdx.x, lane = t & 63, wv = t >> 6, b = blockIdx.x;
    if (b >= nst) return;

    const int rbase = wordL(4 * (lane >> 4), 4 * wv, lane & 15);
    const int wbase = wordL(lane & 15, 2 * (lane >> 4), 4 * wv);
    constexpr int RC[4] = {wordL(0,0,0), wordL(0,1,0), wordL(0,2,0), wordL(0,3,0)};
    constexpr int WCt[4] = {wordL(0,0,0), wordL(0,0,1), wordL(0,0,2), wordL(0,0,3)};

    int cur = 0;
    float myang = 0.f;
#pragma unroll 1
    for (int l = 0; l < 2; ++l) {
        if (l == 0) { if (lane < NQ) myang = x[b * NQ + lane]; }
        else        { if (lane < NQ) myang = ang[48 + lane]; }
        float sv, cv;
        sincosf(0.5f * myang, &sv, &cv);
        float cq[NQ], sq[NQ];
#pragma unroll
        for (int q = 0; q < NQ; ++q) { cq[q] = __shfl(cv, q, 64); sq[q] = __shfl(sv, q, 64); }
        __syncthreads();
        __builtin_amdgcn_sched_barrier(0);

        // ---- init product state (f16, layout L_A, buffer cur) ----
        {
            float Pn = 1.f;
#pragma unroll
            for (int j = 0; j < 4; ++j) Pn *= ((lane >> j) & 1) ? sq[7 - j] : cq[7 - j];
            float Phi = (((lane >> 4) & 1) ? sq[1] : cq[1]) * (((lane >> 4) & 2) ? sq[0] : cq[0]);
            float pre = Pn * Phi;
            float Plo0 = cq[3] * cq[2], Plo1 = sq[3] * cq[2];
            float Plo2 = cq[3] * sq[2], Plo3 = sq[3] * sq[2];
#pragma unroll
            for (int t2 = 0; t2 < 4; ++t2) {
                float Pu = ((t2 & 1) ? sq[11] : cq[11]) * ((t2 & 2) ? sq[10] : cq[10]) *
                           ((wv & 1) ? sq[9] : cq[9]) * ((wv & 2) ? sq[8] : cq[8]);
                float base = pre * Pu;
                uint4 w;
                w.x = pkh(base * Plo0, 0.f);
                w.y = pkh(base * Plo1, 0.f);
                w.z = pkh(base * Plo2, 0.f);
                w.w = pkh(base * Plo3, 0.f);
                *(uint4*)&sbuf[cur * 4096 + (rbase ^ RC[t2])] = w;
            }
        }
        __builtin_amdgcn_sched_barrier(0);
        __syncthreads();
        __builtin_amdgcn_sched_barrier(0);

#pragma unroll 1
        for (int d = 0; d < 6; ++d) {
            const int* pdp = ptabd + d * 12;
            int p0 = pdp[0], p1 = pdp[1], p2 = pdp[2], p3 = pdp[3];
            int p4 = pdp[4], p5 = pdp[5], p6 = pdp[6], p7 = pdp[7];
            int p8 = pdp[8], p9 = pdp[9], p10 = pdp[10], p11 = pdp[11];
            int pb = 0;
            if (lane & 1)  pb ^= p8;
            if (lane & 2)  pb ^= p9;
            if (lane & 4)  pb ^= p10;
            if (lane & 8)  pb ^= p11;
            if (lane & 16) pb ^= p1;
            if (lane & 32) pb ^= p2;
            if (wv & 1)    pb ^= p6;
            if (wv & 2)    pb ^= p7;
#pragma unroll
            for (int ph = 0; ph < 3; ++ph) {
                const int pg = (l * 6 + d) * 3 + ph;
                f16x8 a0 = __builtin_bit_cast(f16x8, frag[(pg * 2 + 0) * 64 + lane]);
                f16x8 a1 = __builtin_bit_cast(f16x8, frag[(pg * 2 + 1) * 64 + lane]);
                const unsigned int* rp = sbuf + cur * 4096;
                f32x4 zero = {0.f, 0.f, 0.f, 0.f};
                f32x4 ac[2][4];
                // ---- read side: all ds_reads of buffer cur, MFMA consume ----
#pragma unroll
                for (int t2 = 0; t2 < 4; ++t2) {
                    f16x8 bf = __builtin_bit_cast(f16x8, *(const uint4*)&rp[rbase ^ RC[t2]]);
                    ac[0][t2] = __builtin_amdgcn_mfma_f32_16x16x32_f16(a0, bf, zero, 0, 0, 0);
                    ac[1][t2] = __builtin_amdgcn_mfma_f32_16x16x32_f16(a1, bf, zero, 0, 0, 0);
                }
                // barrier 1: every wave's reads of buffer cur are complete
                __builtin_amdgcn_sched_barrier(0);
                __syncthreads();
                __builtin_amdgcn_sched_barrier(0);
                // ---- write side: all ds_writes to buffer cur^1 ----
                unsigned int* wp = sbuf + (cur ^ 1) * 4096;
                if (ph < 2) {
#pragma unroll
                    for (int R = 0; R < 2; ++R)
#pragma unroll
                        for (int t2 = 0; t2 < 4; ++t2)
#pragma unroll
                            for (int pr = 0; pr < 2; ++pr) {
                                int word = wbase ^ (32 * pr + 64 * R) ^ WCt[t2];
                                wp[word] = pkh(ac[R][t2][2 * pr], ac[R][t2][2 * pr + 1]);
                            }
                } else {  // phase C: CNOT ring folded into write permutation
#pragma unroll
                    for (int R = 0; R < 2; ++R)
#pragma unroll
                        for (int t2 = 0; t2 < 4; ++t2)
#pragma unroll
                            for (int pr = 0; pr < 2; ++pr) {
                                int sc = (R ? p3 : 0) ^ (pr ? p0 : 0) ^
                                         ((t2 & 1) ? p4 : 0) ^ ((t2 & 2) ? p5 : 0);
                                int word = pb ^ sc;
                                wp[word] = pkh(ac[R][t2][2 * pr], ac[R][t2][2 * pr + 1]);
                            }
                }
                // barrier 2: writes visible before any wave reads cur^1
                __builtin_amdgcn_sched_barrier(0);
                __syncthreads();
                __builtin_amdgcn_sched_barrier(0);
                cur ^= 1;
            }
        }

        // ---- readout from buffer cur (layout L_A) ----
        {
            const unsigned int* rp = sbuf + cur * 4096;
            float P = 0.f, e2 = 0.f, e3 = 0.f, Tt[4];
#pragma unroll
            for (int t2 = 0; t2 < 4; ++t2) {
                uint4 v = *(const uint4*)&rp[rbase ^ RC[t2]];
                unsigned int arr[4] = {v.x, v.y, v.z, v.w};
                float tl = 0.f;
#pragma unroll
                for (int i = 0; i < 4; ++i) {
                    f16x2 h = __builtin_bit_cast(f16x2, arr[i]);
                    float re = (float)h[0], im = (float)h[1];
                    float p = re * re + im * im;
                    tl += p;
                    e2 += (i & 2) ? -p : p;
                    e3 += (i & 1) ? -p : p;
                }
                Tt[t2] = tl; P += tl;
            }
            float r[12];
            r[0] = (lane & 32) ? -P : P;
            r[1] = (lane & 16) ? -P : P;
            r[2] = e2; r[3] = e3;
            r[4] = (lane & 8) ? -P : P;
            r[5] = (lane & 4) ? -P : P;
            r[6] = (lane & 2) ? -P : P;
            r[7] = (lane & 1) ? -P : P;
            r[8] = Tt[0]; r[9] = Tt[1]; r[10] = Tt[2]; r[11] = Tt[3];
#pragma unroll
            for (int k = 0; k < 12; ++k) {
#pragma unroll
                for (int m = 1; m < 64; m <<= 1) r[k] += __shfl_xor(r[k], m, 64);
            }
            if (lane == 0) {
#pragma unroll
                for (int k = 0; k < 12; ++k) ang[wv * 12 + k] = r[k];
            }
            __builtin_amdgcn_sched_barrier(0);
            __syncthreads();
            __builtin_amdgcn_sched_barrier(0);
            if (t < NQ) {
                float E = 0.f;
                if (t < 8) {
                    E = ang[t] + ang[12 + t] + ang[24 + t] + ang[36 + t];
                } else {
#pragma unroll
                    for (int wvi = 0; wvi < 4; ++wvi)
#pragma unroll
                        for (int t2 = 0; t2 < 4; ++t2) {
                            float v = ang[wvi * 12 + 8 + t2];
                            int Tg = 4 * wvi + t2;
                            int bit = (t == 8) ? ((Tg >> 3) & 1) : (t == 9) ? ((Tg >> 2) & 1)
                                    : (t == 10) ? ((Tg >> 1) & 1) : (Tg & 1);
                            E += bit ? -v : v;
                        }
                }
                if (l == 0) ang[48 + t] = E;
                else if (t >= 3 && t < 9) out[b * 6 + (t - 3)] = E * MULT;
            }
            __builtin_amdgcn_sched_barrier(0);
            __syncthreads();
            __builtin_amdgcn_sched_barrier(0);
        }
    }
}

extern "C" void kernel_launch(void* const* d_in, const int* in_sizes, int n_in,
                              void* d_out, int out_size, void* d_ws, size_t ws_size,
                              hipStream_t stream) {
    const float* x = (const float*)d_in[0];
    const float* th = (const float*)d_in[1];
    float* outp = (float*)d_out;
    _Float16* fragh = (_Float16*)d_ws;                    // 73728 B
    int* ptabd = (int*)((char*)d_ws + 73728);             // 288 B

    int batch = in_sizes[0] / NQ;

    hipLaunchKernelGGL(vqc_prep, dim3(18), dim3(256), 0, stream, th, fragh, ptabd);
    hipLaunchKernelGGL(vqc_main, dim3(batch), dim3(256), 0, stream, x,
                       (const uint4*)fragh, ptabd, outp, batch);
}